// Round 12
// baseline (348.704 us; speedup 1.0000x reference)
//
#include <hip/hip_runtime.h>

#define N_NODES 50000
#define N_EDGES 600000
#define IN_DIM 256
#define HID 128
#define OUT_DIM 10
#define BN_EPS 1e-5f

typedef unsigned int uint32;
typedef unsigned short ushort_t;
typedef __attribute__((ext_vector_type(8))) short short8;   // 8 bf16 = 4 VGPRs
typedef __attribute__((ext_vector_type(4))) float float4v;  // MFMA acc

__device__ __forceinline__ unsigned short f2bf_rne(float f) {
    uint32 u = __float_as_uint(f);
    u += 0x7FFF + ((u >> 16) & 1);          // round-to-nearest-even
    return (unsigned short)(u >> 16);
}
__device__ __forceinline__ float bf_lo(uint32 v) { return __uint_as_float(v << 16); }
__device__ __forceinline__ float bf_hi(uint32 v) { return __uint_as_float(v & 0xFFFF0000u); }
__device__ __forceinline__ float bfs(unsigned short s) { return __uint_as_float((uint32)s << 16); }

// ---------------- edge preprocessing: CSR by dst ----------------

__global__ void count_kernel(const int* __restrict__ dst, int* __restrict__ cnt) {
    int e = blockIdx.x * blockDim.x + threadIdx.x;
    if (e < N_EDGES) atomicAdd(&cnt[dst[e]], 1);
}

__global__ __launch_bounds__(256) void assign_kernel(const int* __restrict__ cnt,
                                                     int* __restrict__ row_start,
                                                     int* __restrict__ fill_ptr,
                                                     float* __restrict__ dinv,
                                                     int* __restrict__ cursor) {
    int i = blockIdx.x * blockDim.x + threadIdx.x;
    int c = (i < N_NODES) ? cnt[i] : 0;
    int lane = threadIdx.x & 63;
    int v = c;
    #pragma unroll
    for (int off = 1; off < 64; off <<= 1) {
        int t = __shfl_up(v, off, 64);
        if (lane >= off) v += t;
    }
    int waveTotal = __shfl(v, 63, 64);
    int base = 0;
    if (lane == 63) base = atomicAdd(cursor, waveTotal);
    base = __shfl(base, 63, 64);
    if (i < N_NODES) {
        int start = base + v - c;
        row_start[i] = start;
        fill_ptr[i] = start;
        dinv[i] = rsqrtf((float)c + 1.0f);   // +1 self-loop
    }
}

__global__ void fill_kernel(const int* __restrict__ src, const int* __restrict__ dst,
                            int* __restrict__ fill_ptr, ushort_t* __restrict__ col_src) {
    int e = blockIdx.x * blockDim.x + threadIdx.x;
    if (e < N_EDGES) {
        int d = dst[e];
        int p = atomicAdd(&fill_ptr[d], 1);
        col_src[p] = (ushort_t)src[e];      // src < 50000 < 65536
    }
}

// ---------------- ALL weight packs in one dispatch ----------------
// MFMA B-frag layout: P[((kt*8+nt)*64+lane)*8+j] = bf16( W[kt*32+(lane>>4)*8+j][nt*16+(lane&15)] )

__global__ void pack_w_all(const float* __restrict__ W_in, const float* __restrict__ Wc,
                           unsigned short* __restrict__ PWin, unsigned short* __restrict__ PWc) {
    int idx = blockIdx.x * blockDim.x + threadIdx.x;
    if (idx >= 4096 + 3 * 2048) return;
    const float* W;
    unsigned short* P;
    int r;
    if (idx < 4096) { W = W_in; P = PWin + (size_t)idx * 8; r = idx; }
    else {
        int t = idx - 4096;
        int layer = t / 2048;
        r = t - layer * 2048;
        W = Wc + (size_t)layer * HID * HID;
        P = PWc + (size_t)(layer * 2048 + r) * 8;
    }
    int lane = r & 63;
    int nt = (r >> 6) & 7;
    int kt = r >> 9;
    int n = nt * 16 + (lane & 15);
    int kbase = kt * 32 + (lane >> 4) * 8;
    #pragma unroll
    for (int j = 0; j < 8; ++j) P[j] = f2bf_rne(W[(size_t)(kbase + j) * HID + n]);
}

// ---------------- fused input projection + layer-0 message GEMM ----------------
// h0 = relu(x@W_in + b_in) in regs/LDS only; B16 = (h0 @ Wc0) * dinv[row].
// MFMA mappings (m89-verified): A[m=lane&15][k=quad*8+j]; D: col=lane&15, row=quad*4+reg.

__global__ __launch_bounds__(256) void gemm_in_fused(const float* __restrict__ x,
                                                     const unsigned short* __restrict__ PWin,
                                                     const unsigned short* __restrict__ PWc0,
                                                     const float* __restrict__ b_in,
                                                     const float* __restrict__ dinv,
                                                     unsigned short* __restrict__ B16, int M) {
    __shared__ unsigned short As[64 * 40];     // x staging, stride 40 (2-way alias, free)
    __shared__ unsigned short Hs[64 * 136];    // h0 tile
    int tid = threadIdx.x;
    int w = tid >> 6, lane = tid & 63;
    int mrow = lane & 15, quad = lane >> 4;
    int m0 = blockIdx.x * 64;

    float4v acc[8];
    #pragma unroll
    for (int nt = 0; nt < 8; ++nt)
        #pragma unroll
        for (int i = 0; i < 4; ++i) acc[nt][i] = 0.f;

    int r = tid >> 2;        // staging row
    int cq = tid & 3;        // col quarter (8 floats)

    for (int kt = 0; kt < IN_DIM / 32; ++kt) {
        short8 pk;
        int row = m0 + r;
        if (row < M) {
            const float* srcp = x + (size_t)row * IN_DIM + kt * 32 + cq * 8;
            float4 a0 = *(const float4*)(srcp);
            float4 a1 = *(const float4*)(srcp + 4);
            pk[0] = (short)f2bf_rne(a0.x); pk[1] = (short)f2bf_rne(a0.y);
            pk[2] = (short)f2bf_rne(a0.z); pk[3] = (short)f2bf_rne(a0.w);
            pk[4] = (short)f2bf_rne(a1.x); pk[5] = (short)f2bf_rne(a1.y);
            pk[6] = (short)f2bf_rne(a1.z); pk[7] = (short)f2bf_rne(a1.w);
        } else {
            #pragma unroll
            for (int j = 0; j < 8; ++j) pk[j] = 0;
        }
        __syncthreads();
        *(short8*)&As[r * 40 + cq * 8] = pk;
        __syncthreads();

        short8 afrag = *(const short8*)&As[(w * 16 + mrow) * 40 + quad * 8];
        const unsigned short* pb = PWin + ((size_t)(kt * 8) * 64 + lane) * 8;
        #pragma unroll
        for (int nt = 0; nt < 8; ++nt) {
            short8 bfrag = *(const short8*)(pb + (size_t)nt * 64 * 8);
            acc[nt] = __builtin_amdgcn_mfma_f32_16x16x32_bf16(afrag, bfrag, acc[nt], 0, 0, 0);
        }
    }

    // epilogue-1: h0 = relu(acc + b_in) -> Hs (D-layout: row=w*16+quad*4+reg, col=nt*16+mrow)
    int rl = w * 16 + quad * 4;
    #pragma unroll
    for (int nt = 0; nt < 8; ++nt) {
        int col = nt * 16 + mrow;
        float bv = b_in[col];
        #pragma unroll
        for (int reg = 0; reg < 4; ++reg) {
            float h = fmaxf(acc[nt][reg] + bv, 0.f);
            Hs[(rl + reg) * 136 + col] = f2bf_rne(h);
        }
    }
    __syncthreads();

    // second GEMM: B = h0 @ Wc0 (K=128 from Hs)
    float4v acc2[8];
    #pragma unroll
    for (int nt = 0; nt < 8; ++nt)
        #pragma unroll
        for (int i = 0; i < 4; ++i) acc2[nt][i] = 0.f;

    #pragma unroll
    for (int kt = 0; kt < 4; ++kt) {
        short8 af2 = *(const short8*)&Hs[(w * 16 + mrow) * 136 + kt * 32 + quad * 8];
        const unsigned short* pb = PWc0 + ((size_t)(kt * 8) * 64 + lane) * 8;
        #pragma unroll
        for (int nt = 0; nt < 8; ++nt) {
            short8 bfrag = *(const short8*)(pb + (size_t)nt * 64 * 8);
            acc2[nt] = __builtin_amdgcn_mfma_f32_16x16x32_bf16(af2, bfrag, acc2[nt], 0, 0, 0);
        }
    }

    // epilogue-2: B16 = acc2 * dinv[row]
    int rowbase = m0 + w * 16 + quad * 4;
    float rs[4];
    #pragma unroll
    for (int reg = 0; reg < 4; ++reg) {
        int row = rowbase + reg;
        rs[reg] = (row < M) ? dinv[row] : 0.f;
    }
    #pragma unroll
    for (int nt = 0; nt < 8; ++nt) {
        int col = nt * 16 + mrow;
        #pragma unroll
        for (int reg = 0; reg < 4; ++reg) {
            int row = rowbase + reg;
            if (row < M) B16[(size_t)row * HID + col] = f2bf_rne(acc2[nt][reg] * rs[reg]);
        }
    }
}

// ---------------- fused CSR pull aggregation + BN column stats (C out = bf16) ----------------
// One node per wave, grid 12500 x (64,4); masked clamped unroll-16: 94% of Poisson(12)
// nodes finish in ONE iteration with 16 gathers in flight (clamp duplicates hit same line).
// Stats: LDS reduce -> 32 hashed global accumulators.

__global__ __launch_bounds__(256) void agg_stats_kernel(const uint32* __restrict__ Bs32,  // [N][64]
                                                        const float* __restrict__ dinv,
                                                        const int* __restrict__ row_start,
                                                        const int* __restrict__ cnt,
                                                        const ushort_t* __restrict__ col_src,
                                                        const float* __restrict__ bc,
                                                        uint32* __restrict__ C16,         // [N][64]
                                                        float* __restrict__ colsum_multi) { // [32][256]
    __shared__ float shs[4][128];
    __shared__ float shq[4][128];
    int f2 = threadIdx.x;              // 0..63
    int ty = threadIdx.y;              // 0..3
    int n = blockIdx.x * 4 + ty;       // N_NODES % 4 == 0

    uint32 vs = Bs32[(size_t)n * 64 + f2];          // self term
    float acc0 = bf_lo(vs);
    float acc1 = bf_hi(vs);

    int beg = row_start[n];
    int end = beg + cnt[n];
    for (int e = beg; e < end; e += 16) {
        int last = end - 1;
        int idx[16];
        #pragma unroll
        for (int k = 0; k < 16; ++k) idx[k] = (e + k < end) ? (e + k) : last;
        int s[16];
        #pragma unroll
        for (int k = 0; k < 16; ++k) s[k] = col_src[idx[k]];   // wave-uniform (scalar path)
        uint32 v[16];
        #pragma unroll
        for (int k = 0; k < 16; ++k) v[k] = Bs32[(size_t)s[k] * 64 + f2];
        acc0 += bf_lo(v[0]); acc1 += bf_hi(v[0]);
        #pragma unroll
        for (int k = 1; k < 16; ++k) {
            float m = (e + k < end) ? 1.f : 0.f;
            acc0 += m * bf_lo(v[k]);
            acc1 += m * bf_hi(v[k]);
        }
    }

    float di = dinv[n];
    float2 bcv = *(const float2*)(bc + f2 * 2);
    float o0 = acc0 * di + bcv.x;
    float o1 = acc1 * di + bcv.y;
    C16[(size_t)n * 64 + f2] = (uint32)f2bf_rne(o0) | ((uint32)f2bf_rne(o1) << 16);

    shs[ty][f2 * 2] = o0; shs[ty][f2 * 2 + 1] = o1;
    shq[ty][f2 * 2] = o0 * o0; shq[ty][f2 * 2 + 1] = o1 * o1;
    __syncthreads();
    int t = ty * 64 + f2;              // 0..255
    if (t < 128) {
        float s = shs[0][t] + shs[1][t] + shs[2][t] + shs[3][t];
        float q = shq[0][t] + shq[1][t] + shq[2][t] + shq[3][t];
        float* base = colsum_multi + (size_t)(blockIdx.x & 31) * 256;
        atomicAdd(&base[t], s);
        atomicAdd(&base[t + 128], q);
    }
}

// ---------------- fused BN-finalize + BN-apply + residual + next message GEMM ----------------
// In-kernel finalize; staging: h = relu(bf16(C)*sc+sh) (+A16 if RES);
// writes bf16(h) -> A16 and -> LDS -> MFMA with next layer's Wc; B16 = (h@Wc)*dinv.

template <int RES>
__global__ __launch_bounds__(256) void gemm_bn_fused(const unsigned short* __restrict__ C16,
                                                     const unsigned short* __restrict__ PB,
                                                     const float* __restrict__ colsum_multi,
                                                     const float* __restrict__ gamma,
                                                     const float* __restrict__ beta,
                                                     const float* __restrict__ dinv,
                                                     unsigned short* __restrict__ A16,
                                                     unsigned short* __restrict__ B16, int M) {
    __shared__ unsigned short As[64 * 40];
    __shared__ float scs[128], shb[128];
    int tid = threadIdx.x;
    int w = tid >> 6, lane = tid & 63;
    int mrow = lane & 15, quad = lane >> 4;
    int m0 = blockIdx.x * 64;

    if (tid < 128) {                       // in-block BN finalize
        float s = 0.f, q = 0.f;
        #pragma unroll
        for (int c = 0; c < 32; ++c) {
            s += colsum_multi[c * 256 + tid];
            q += colsum_multi[c * 256 + tid + 128];
        }
        float mu = s * (1.0f / N_NODES);
        float var = q * (1.0f / N_NODES) - mu * mu;
        float rstd = rsqrtf(var + BN_EPS);
        float sc = rstd * gamma[tid];
        scs[tid] = sc;
        shb[tid] = beta[tid] - mu * sc;
    }
    __syncthreads();

    float4v acc[8];
    #pragma unroll
    for (int nt = 0; nt < 8; ++nt)
        #pragma unroll
        for (int i = 0; i < 4; ++i) acc[nt][i] = 0.f;

    int r = tid >> 2;
    int cq = tid & 3;

    for (int kt = 0; kt < 4; ++kt) {
        short8 pk;
        int row = m0 + r;
        int col0 = kt * 32 + cq * 8;
        if (row < M) {
            short8 cv = *(const short8*)(C16 + (size_t)row * HID + col0);
            float h[8];
            #pragma unroll
            for (int j = 0; j < 8; ++j)
                h[j] = fmaxf(bfs((unsigned short)cv[j]) * scs[col0 + j] + shb[col0 + j], 0.f);
            unsigned short* ap = A16 + (size_t)row * HID + col0;
            if (RES) {
                short8 av = *(const short8*)(ap);
                #pragma unroll
                for (int j = 0; j < 8; ++j) h[j] += bfs((unsigned short)av[j]);
            }
            #pragma unroll
            for (int j = 0; j < 8; ++j) pk[j] = (short)f2bf_rne(h[j]);
            *(short8*)(ap) = pk;
        } else {
            #pragma unroll
            for (int j = 0; j < 8; ++j) pk[j] = 0;
        }
        __syncthreads();
        *(short8*)&As[r * 40 + cq * 8] = pk;
        __syncthreads();

        short8 afrag = *(const short8*)&As[(w * 16 + mrow) * 40 + quad * 8];
        const unsigned short* pb = PB + ((size_t)(kt * 8) * 64 + lane) * 8;
        #pragma unroll
        for (int nt = 0; nt < 8; ++nt) {
            short8 bfrag = *(const short8*)(pb + (size_t)nt * 64 * 8);
            acc[nt] = __builtin_amdgcn_mfma_f32_16x16x32_bf16(afrag, bfrag, acc[nt], 0, 0, 0);
        }
    }

    int rowbase = m0 + w * 16 + quad * 4;
    float rs[4];
    #pragma unroll
    for (int reg = 0; reg < 4; ++reg) {
        int row = rowbase + reg;
        rs[reg] = (row < M) ? dinv[row] : 0.f;
    }
    #pragma unroll
    for (int nt = 0; nt < 8; ++nt) {
        int col = nt * 16 + mrow;
        #pragma unroll
        for (int reg = 0; reg < 4; ++reg) {
            int row = rowbase + reg;
            if (row < M) B16[(size_t)row * HID + col] = f2bf_rne(acc[nt][reg] * rs[reg]);
        }
    }
}

// ---------------- fused final BN-finalize+apply + output projection ----------------
// h3 = relu(bf16(C)*sc+sh) + A16 (LDS only); out = h3 @ Wo + bo.

__global__ __launch_bounds__(256) void out_fused(const uint32* __restrict__ C16,  // [N][64]
                                                 const uint32* __restrict__ A16,  // [N][64]
                                                 const float* __restrict__ colsum_multi,
                                                 const float* __restrict__ gamma,
                                                 const float* __restrict__ beta,
                                                 const float* __restrict__ Wo,
                                                 const float* __restrict__ bo,
                                                 float* __restrict__ out) {
    __shared__ float Hs[64][132];          // pad 4
    __shared__ float WoS[HID * OUT_DIM];
    __shared__ float scs[128], shb[128];
    int tid = threadIdx.x;
    for (int i = tid; i < HID * OUT_DIM; i += 256) WoS[i] = Wo[i];
    if (tid < 128) {
        float s = 0.f, q = 0.f;
        #pragma unroll
        for (int c = 0; c < 32; ++c) {
            s += colsum_multi[c * 256 + tid];
            q += colsum_multi[c * 256 + tid + 128];
        }
        float mu = s * (1.0f / N_NODES);
        float var = q * (1.0f / N_NODES) - mu * mu;
        float rstd = rsqrtf(var + BN_EPS);
        float sc = rstd * gamma[tid];
        scs[tid] = sc;
        shb[tid] = beta[tid] - mu * sc;
    }
    __syncthreads();

    int n0 = blockIdx.x * 64;
    #pragma unroll
    for (int i = 0; i < 8; ++i) {
        int lin = i * 256 + tid;           // 0..2047
        int row = lin >> 5;                // 0..63
        int colq = lin & 31;               // 4-feature group
        int n = n0 + row;
        float4 h = make_float4(0.f, 0.f, 0.f, 0.f);
        if (n < N_NODES) {
            uint2 cv = ((const uint2*)C16)[(size_t)n * 32 + colq];
            uint2 av = ((const uint2*)A16)[(size_t)n * 32 + colq];
            float c0 = bf_lo(cv.x), c1 = bf_hi(cv.x), c2 = bf_lo(cv.y), c3 = bf_hi(cv.y);
            float4 s = *(const float4*)(scs + colq * 4);
            float4 t = *(const float4*)(shb + colq * 4);
            h.x = fmaxf(c0 * s.x + t.x, 0.f) + bf_lo(av.x);
            h.y = fmaxf(c1 * s.y + t.y, 0.f) + bf_hi(av.x);
            h.z = fmaxf(c2 * s.z + t.z, 0.f) + bf_lo(av.y);
            h.w = fmaxf(c3 * s.w + t.w, 0.f) + bf_hi(av.y);
        }
        *(float4*)&Hs[row][colq * 4] = h;
    }
    __syncthreads();

    #pragma unroll
    for (int j = 0; j < 3; ++j) {
        int o = j * 256 + tid;             // 0..639
        if (o < 64 * OUT_DIM) {
            int nl = o / OUT_DIM;
            int c = o - nl * OUT_DIM;
            int n = n0 + nl;
            if (n < N_NODES) {
                float s = 0.f;
                #pragma unroll 4
                for (int k = 0; k < HID; ++k) s += Hs[nl][k] * WoS[k * OUT_DIM + c];
                out[(size_t)n * OUT_DIM + c] = s + bo[c];
            }
        }
    }
}

// ---------------- launch ----------------

extern "C" void kernel_launch(void* const* d_in, const int* in_sizes, int n_in,
                              void* d_out, int out_size, void* d_ws, size_t ws_size,
                              hipStream_t stream) {
    const float* x     = (const float*)d_in[0];
    const int*   ei    = (const int*)d_in[1];
    const int*   src   = ei;
    const int*   dst   = ei + N_EDGES;
    const float* W_in  = (const float*)d_in[2];
    const float* b_in  = (const float*)d_in[3];
    const float* Wc    = (const float*)d_in[4];
    const float* bc    = (const float*)d_in[5];
    const float* gamma = (const float*)d_in[6];
    const float* beta  = (const float*)d_in[7];
    const float* W_out = (const float*)d_in[8];
    const float* b_out = (const float*)d_in[9];
    float* out = (float*)d_out;

    char* p = (char*)d_ws;
    auto alloc = [&](size_t bytes) -> char* {
        char* q = p;
        p += (bytes + 255) & ~(size_t)255;
        return q;
    };
    unsigned short* A16 = (unsigned short*)alloc(sizeof(unsigned short) * N_NODES * HID); // residual h bf16
    unsigned short* B16 = (unsigned short*)alloc(sizeof(unsigned short) * N_NODES * HID); // messages bf16
    uint32* C16       = (uint32*)alloc(sizeof(unsigned short) * N_NODES * HID);           // aggregated bf16
    float*  dinv      = (float*)alloc(sizeof(float) * N_NODES);
    int*    deg_cnt   = (int*)alloc(sizeof(int) * (N_NODES + 1));            // last int = cursor
    int*    cursor    = deg_cnt + N_NODES;
    int*    row_start = (int*)alloc(sizeof(int) * N_NODES);
    int*    fill_ptr  = (int*)alloc(sizeof(int) * N_NODES);
    ushort_t* col_src = (ushort_t*)alloc(sizeof(ushort_t) * N_EDGES);
    unsigned short* PWin = (unsigned short*)alloc(sizeof(unsigned short) * 4096 * 8);
    unsigned short* PWc  = (unsigned short*)alloc(sizeof(unsigned short) * 3 * 2048 * 8);
    float*  colsumAll = (float*)alloc(sizeof(float) * 3 * 32 * 256);         // 32 hashed copies per layer

    // CSR build
    hipMemsetAsync(deg_cnt, 0, sizeof(int) * (N_NODES + 1), stream);
    hipMemsetAsync(colsumAll, 0, sizeof(float) * 3 * 32 * 256, stream);
    count_kernel<<<(N_EDGES + 255) / 256, 256, 0, stream>>>(dst, deg_cnt);
    assign_kernel<<<(N_NODES + 255) / 256, 256, 0, stream>>>(deg_cnt, row_start, fill_ptr, dinv, cursor);
    fill_kernel<<<(N_EDGES + 255) / 256, 256, 0, stream>>>(src, dst, fill_ptr, col_src);

    // all weight packs (W_in + 3x Wc), one dispatch
    pack_w_all<<<(4096 + 3 * 2048 + 255) / 256, 256, 0, stream>>>(W_in, Wc, PWin, PWc);

    const int gblk = (N_NODES + 63) / 64;

    // fused input projection + layer-0 message gemm: B0 = (relu(x@W_in+b) @ Wc0) * dinv
    gemm_in_fused<<<gblk, 256, 0, stream>>>(x, PWin, PWc, b_in, dinv, B16, N_NODES);

    for (int l = 0; l < 3; ++l) {
        float* colsum = colsumAll + (size_t)l * 32 * 256;
        agg_stats_kernel<<<N_NODES / 4, dim3(64, 4), 0, stream>>>(
            (const uint32*)B16, dinv, row_start, deg_cnt, col_src, bc + l * HID, C16, colsum);
        if (l == 0) {
            gemm_bn_fused<0><<<gblk, 256, 0, stream>>>(
                (const unsigned short*)C16, PWc + (size_t)1 * 2048 * 8, colsum,
                gamma, beta, dinv, A16, B16, N_NODES);
        } else if (l == 1) {
            gemm_bn_fused<1><<<gblk, 256, 0, stream>>>(
                (const unsigned short*)C16, PWc + (size_t)2 * 2048 * 8, colsum,
                gamma + HID, beta + HID, dinv, A16, B16, N_NODES);
        } else {
            out_fused<<<gblk, 256, 0, stream>>>(
                C16, (const uint32*)A16, colsum, gamma + 2 * HID, beta + 2 * HID, W_out, b_out, out);
        }
    }
}

// Round 13
// 344.819 us; speedup vs baseline: 1.0113x; 1.0113x over previous
//
#include <hip/hip_runtime.h>

#define N_NODES 50000
#define N_EDGES 600000
#define IN_DIM 256
#define HID 128
#define OUT_DIM 10
#define BN_EPS 1e-5f

typedef unsigned int uint32;
typedef unsigned short ushort_t;
typedef __attribute__((ext_vector_type(8))) short short8;   // 8 bf16 = 4 VGPRs
typedef __attribute__((ext_vector_type(4))) float float4v;  // MFMA acc

__device__ __forceinline__ unsigned short f2bf_rne(float f) {
    uint32 u = __float_as_uint(f);
    u += 0x7FFF + ((u >> 16) & 1);          // round-to-nearest-even
    return (unsigned short)(u >> 16);
}
__device__ __forceinline__ float bf_lo(uint32 v) { return __uint_as_float(v << 16); }
__device__ __forceinline__ float bf_hi(uint32 v) { return __uint_as_float(v & 0xFFFF0000u); }
__device__ __forceinline__ float bfs(unsigned short s) { return __uint_as_float((uint32)s << 16); }

// ---------------- edge preprocessing: CSR by dst ----------------

__global__ void count_kernel(const int* __restrict__ dst, int* __restrict__ cnt) {
    int e = blockIdx.x * blockDim.x + threadIdx.x;
    if (e < N_EDGES) atomicAdd(&cnt[dst[e]], 1);
}

__global__ __launch_bounds__(256) void assign_kernel(const int* __restrict__ cnt,
                                                     int* __restrict__ row_start,
                                                     int* __restrict__ fill_ptr,
                                                     float* __restrict__ dinv,
                                                     int* __restrict__ cursor) {
    int i = blockIdx.x * blockDim.x + threadIdx.x;
    int c = (i < N_NODES) ? cnt[i] : 0;
    int lane = threadIdx.x & 63;
    int v = c;
    #pragma unroll
    for (int off = 1; off < 64; off <<= 1) {
        int t = __shfl_up(v, off, 64);
        if (lane >= off) v += t;
    }
    int waveTotal = __shfl(v, 63, 64);
    int base = 0;
    if (lane == 63) base = atomicAdd(cursor, waveTotal);
    base = __shfl(base, 63, 64);
    if (i < N_NODES) {
        int start = base + v - c;
        row_start[i] = start;
        fill_ptr[i] = start;
        dinv[i] = rsqrtf((float)c + 1.0f);   // +1 self-loop
    }
}

__global__ void fill_kernel(const int* __restrict__ src, const int* __restrict__ dst,
                            int* __restrict__ fill_ptr, ushort_t* __restrict__ col_src) {
    int e = blockIdx.x * blockDim.x + threadIdx.x;
    if (e < N_EDGES) {
        int d = dst[e];
        int p = atomicAdd(&fill_ptr[d], 1);
        col_src[p] = (ushort_t)src[e];      // src < 50000 < 65536
    }
}

// ---------------- ALL weight packs in one dispatch ----------------
// MFMA B-frag layout: P[((kt*8+nt)*64+lane)*8+j] = bf16( W[kt*32+(lane>>4)*8+j][nt*16+(lane&15)] )

__global__ void pack_w_all(const float* __restrict__ W_in, const float* __restrict__ Wc,
                           unsigned short* __restrict__ PWin, unsigned short* __restrict__ PWc) {
    int idx = blockIdx.x * blockDim.x + threadIdx.x;
    if (idx >= 4096 + 3 * 2048) return;
    const float* W;
    unsigned short* P;
    int r;
    if (idx < 4096) { W = W_in; P = PWin + (size_t)idx * 8; r = idx; }
    else {
        int t = idx - 4096;
        int layer = t / 2048;
        r = t - layer * 2048;
        W = Wc + (size_t)layer * HID * HID;
        P = PWc + (size_t)(layer * 2048 + r) * 8;
    }
    int lane = r & 63;
    int nt = (r >> 6) & 7;
    int kt = r >> 9;
    int n = nt * 16 + (lane & 15);
    int kbase = kt * 32 + (lane >> 4) * 8;
    #pragma unroll
    for (int j = 0; j < 8; ++j) P[j] = f2bf_rne(W[(size_t)(kbase + j) * HID + n]);
}

// ---------------- fused input projection + layer-0 message GEMM ----------------
// h0 = relu(x@W_in + b_in) in regs/LDS only; B16 = (h0 @ Wc0) * dinv[row].
// MFMA mappings (m89-verified): A[m=lane&15][k=quad*8+j]; D: col=lane&15, row=quad*4+reg.

__global__ __launch_bounds__(256) void gemm_in_fused(const float* __restrict__ x,
                                                     const unsigned short* __restrict__ PWin,
                                                     const unsigned short* __restrict__ PWc0,
                                                     const float* __restrict__ b_in,
                                                     const float* __restrict__ dinv,
                                                     unsigned short* __restrict__ B16, int M) {
    __shared__ unsigned short As[64 * 40];     // x staging, stride 40 (2-way alias, free)
    __shared__ unsigned short Hs[64 * 136];    // h0 tile
    int tid = threadIdx.x;
    int w = tid >> 6, lane = tid & 63;
    int mrow = lane & 15, quad = lane >> 4;
    int m0 = blockIdx.x * 64;

    float4v acc[8];
    #pragma unroll
    for (int nt = 0; nt < 8; ++nt)
        #pragma unroll
        for (int i = 0; i < 4; ++i) acc[nt][i] = 0.f;

    int r = tid >> 2;        // staging row
    int cq = tid & 3;        // col quarter (8 floats)

    for (int kt = 0; kt < IN_DIM / 32; ++kt) {
        short8 pk;
        int row = m0 + r;
        if (row < M) {
            const float* srcp = x + (size_t)row * IN_DIM + kt * 32 + cq * 8;
            float4 a0 = *(const float4*)(srcp);
            float4 a1 = *(const float4*)(srcp + 4);
            pk[0] = (short)f2bf_rne(a0.x); pk[1] = (short)f2bf_rne(a0.y);
            pk[2] = (short)f2bf_rne(a0.z); pk[3] = (short)f2bf_rne(a0.w);
            pk[4] = (short)f2bf_rne(a1.x); pk[5] = (short)f2bf_rne(a1.y);
            pk[6] = (short)f2bf_rne(a1.z); pk[7] = (short)f2bf_rne(a1.w);
        } else {
            #pragma unroll
            for (int j = 0; j < 8; ++j) pk[j] = 0;
        }
        __syncthreads();
        *(short8*)&As[r * 40 + cq * 8] = pk;
        __syncthreads();

        short8 afrag = *(const short8*)&As[(w * 16 + mrow) * 40 + quad * 8];
        const unsigned short* pb = PWin + ((size_t)(kt * 8) * 64 + lane) * 8;
        #pragma unroll
        for (int nt = 0; nt < 8; ++nt) {
            short8 bfrag = *(const short8*)(pb + (size_t)nt * 64 * 8);
            acc[nt] = __builtin_amdgcn_mfma_f32_16x16x32_bf16(afrag, bfrag, acc[nt], 0, 0, 0);
        }
    }

    // epilogue-1: h0 = relu(acc + b_in) -> Hs (D-layout: row=w*16+quad*4+reg, col=nt*16+mrow)
    int rl = w * 16 + quad * 4;
    #pragma unroll
    for (int nt = 0; nt < 8; ++nt) {
        int col = nt * 16 + mrow;
        float bv = b_in[col];
        #pragma unroll
        for (int reg = 0; reg < 4; ++reg) {
            float h = fmaxf(acc[nt][reg] + bv, 0.f);
            Hs[(rl + reg) * 136 + col] = f2bf_rne(h);
        }
    }
    __syncthreads();

    // second GEMM: B = h0 @ Wc0 (K=128 from Hs)
    float4v acc2[8];
    #pragma unroll
    for (int nt = 0; nt < 8; ++nt)
        #pragma unroll
        for (int i = 0; i < 4; ++i) acc2[nt][i] = 0.f;

    #pragma unroll
    for (int kt = 0; kt < 4; ++kt) {
        short8 af2 = *(const short8*)&Hs[(w * 16 + mrow) * 136 + kt * 32 + quad * 8];
        const unsigned short* pb = PWc0 + ((size_t)(kt * 8) * 64 + lane) * 8;
        #pragma unroll
        for (int nt = 0; nt < 8; ++nt) {
            short8 bfrag = *(const short8*)(pb + (size_t)nt * 64 * 8);
            acc2[nt] = __builtin_amdgcn_mfma_f32_16x16x32_bf16(af2, bfrag, acc2[nt], 0, 0, 0);
        }
    }

    // epilogue-2: B16 = acc2 * dinv[row]
    int rowbase = m0 + w * 16 + quad * 4;
    float rs[4];
    #pragma unroll
    for (int reg = 0; reg < 4; ++reg) {
        int row = rowbase + reg;
        rs[reg] = (row < M) ? dinv[row] : 0.f;
    }
    #pragma unroll
    for (int nt = 0; nt < 8; ++nt) {
        int col = nt * 16 + mrow;
        #pragma unroll
        for (int reg = 0; reg < 4; ++reg) {
            int row = rowbase + reg;
            if (row < M) B16[(size_t)row * HID + col] = f2bf_rne(acc2[nt][reg] * rs[reg]);
        }
    }
}

// ---------------- fused CSR pull aggregation + BN column stats (C out = bf16) ----------------
// One node per wave, grid 12500 x (64,4); masked clamped unroll-8 (8 gathers in flight —
// measured optimum: 4 -> 8 helped, 8 -> 16 regressed). Stats: LDS reduce -> 32 hashed accums.

__global__ __launch_bounds__(256) void agg_stats_kernel(const uint32* __restrict__ Bs32,  // [N][64]
                                                        const float* __restrict__ dinv,
                                                        const int* __restrict__ row_start,
                                                        const int* __restrict__ cnt,
                                                        const ushort_t* __restrict__ col_src,
                                                        const float* __restrict__ bc,
                                                        uint32* __restrict__ C16,         // [N][64]
                                                        float* __restrict__ colsum_multi) { // [32][256]
    __shared__ float shs[4][128];
    __shared__ float shq[4][128];
    int f2 = threadIdx.x;              // 0..63
    int ty = threadIdx.y;              // 0..3
    int n = blockIdx.x * 4 + ty;       // N_NODES % 4 == 0

    uint32 vs = Bs32[(size_t)n * 64 + f2];          // self term
    float acc0 = bf_lo(vs);
    float acc1 = bf_hi(vs);

    int beg = row_start[n];
    int end = beg + cnt[n];
    for (int e = beg; e < end; e += 8) {
        int last = end - 1;
        int idx[8];
        #pragma unroll
        for (int k = 0; k < 8; ++k) idx[k] = (e + k < end) ? (e + k) : last;
        int s[8];
        #pragma unroll
        for (int k = 0; k < 8; ++k) s[k] = col_src[idx[k]];
        uint32 v[8];
        #pragma unroll
        for (int k = 0; k < 8; ++k) v[k] = Bs32[(size_t)s[k] * 64 + f2];
        acc0 += bf_lo(v[0]); acc1 += bf_hi(v[0]);
        #pragma unroll
        for (int k = 1; k < 8; ++k) {
            float m = (e + k < end) ? 1.f : 0.f;
            acc0 += m * bf_lo(v[k]);
            acc1 += m * bf_hi(v[k]);
        }
    }

    float di = dinv[n];
    float2 bcv = *(const float2*)(bc + f2 * 2);
    float o0 = acc0 * di + bcv.x;
    float o1 = acc1 * di + bcv.y;
    C16[(size_t)n * 64 + f2] = (uint32)f2bf_rne(o0) | ((uint32)f2bf_rne(o1) << 16);

    shs[ty][f2 * 2] = o0; shs[ty][f2 * 2 + 1] = o1;
    shq[ty][f2 * 2] = o0 * o0; shq[ty][f2 * 2 + 1] = o1 * o1;
    __syncthreads();
    int t = ty * 64 + f2;              // 0..255
    if (t < 128) {
        float s = shs[0][t] + shs[1][t] + shs[2][t] + shs[3][t];
        float q = shq[0][t] + shq[1][t] + shq[2][t] + shq[3][t];
        float* base = colsum_multi + (size_t)(blockIdx.x & 31) * 256;
        atomicAdd(&base[t], s);
        atomicAdd(&base[t + 128], q);
    }
}

// ---------------- fused BN-finalize + BN-apply + residual + next message GEMM ----------------
// In-kernel finalize; staging: h = relu(bf16(C)*sc+sh) (+A16 if RES);
// writes bf16(h) -> A16 and -> LDS -> MFMA with next layer's Wc; B16 = (h@Wc)*dinv.

template <int RES>
__global__ __launch_bounds__(256) void gemm_bn_fused(const unsigned short* __restrict__ C16,
                                                     const unsigned short* __restrict__ PB,
                                                     const float* __restrict__ colsum_multi,
                                                     const float* __restrict__ gamma,
                                                     const float* __restrict__ beta,
                                                     const float* __restrict__ dinv,
                                                     unsigned short* __restrict__ A16,
                                                     unsigned short* __restrict__ B16, int M) {
    __shared__ unsigned short As[64 * 40];
    __shared__ float scs[128], shb[128];
    int tid = threadIdx.x;
    int w = tid >> 6, lane = tid & 63;
    int mrow = lane & 15, quad = lane >> 4;
    int m0 = blockIdx.x * 64;

    if (tid < 128) {                       // in-block BN finalize
        float s = 0.f, q = 0.f;
        #pragma unroll
        for (int c = 0; c < 32; ++c) {
            s += colsum_multi[c * 256 + tid];
            q += colsum_multi[c * 256 + tid + 128];
        }
        float mu = s * (1.0f / N_NODES);
        float var = q * (1.0f / N_NODES) - mu * mu;
        float rstd = rsqrtf(var + BN_EPS);
        float sc = rstd * gamma[tid];
        scs[tid] = sc;
        shb[tid] = beta[tid] - mu * sc;
    }
    __syncthreads();

    float4v acc[8];
    #pragma unroll
    for (int nt = 0; nt < 8; ++nt)
        #pragma unroll
        for (int i = 0; i < 4; ++i) acc[nt][i] = 0.f;

    int r = tid >> 2;
    int cq = tid & 3;

    for (int kt = 0; kt < 4; ++kt) {
        short8 pk;
        int row = m0 + r;
        int col0 = kt * 32 + cq * 8;
        if (row < M) {
            short8 cv = *(const short8*)(C16 + (size_t)row * HID + col0);
            float h[8];
            #pragma unroll
            for (int j = 0; j < 8; ++j)
                h[j] = fmaxf(bfs((unsigned short)cv[j]) * scs[col0 + j] + shb[col0 + j], 0.f);
            unsigned short* ap = A16 + (size_t)row * HID + col0;
            if (RES) {
                short8 av = *(const short8*)(ap);
                #pragma unroll
                for (int j = 0; j < 8; ++j) h[j] += bfs((unsigned short)av[j]);
            }
            #pragma unroll
            for (int j = 0; j < 8; ++j) pk[j] = (short)f2bf_rne(h[j]);
            *(short8*)(ap) = pk;
        } else {
            #pragma unroll
            for (int j = 0; j < 8; ++j) pk[j] = 0;
        }
        __syncthreads();
        *(short8*)&As[r * 40 + cq * 8] = pk;
        __syncthreads();

        short8 afrag = *(const short8*)&As[(w * 16 + mrow) * 40 + quad * 8];
        const unsigned short* pb = PB + ((size_t)(kt * 8) * 64 + lane) * 8;
        #pragma unroll
        for (int nt = 0; nt < 8; ++nt) {
            short8 bfrag = *(const short8*)(pb + (size_t)nt * 64 * 8);
            acc[nt] = __builtin_amdgcn_mfma_f32_16x16x32_bf16(afrag, bfrag, acc[nt], 0, 0, 0);
        }
    }

    int rowbase = m0 + w * 16 + quad * 4;
    float rs[4];
    #pragma unroll
    for (int reg = 0; reg < 4; ++reg) {
        int row = rowbase + reg;
        rs[reg] = (row < M) ? dinv[row] : 0.f;
    }
    #pragma unroll
    for (int nt = 0; nt < 8; ++nt) {
        int col = nt * 16 + mrow;
        #pragma unroll
        for (int reg = 0; reg < 4; ++reg) {
            int row = rowbase + reg;
            if (row < M) B16[(size_t)row * HID + col] = f2bf_rne(acc[nt][reg] * rs[reg]);
        }
    }
}

// ---------------- fused final BN-finalize+apply + output projection ----------------
// h3 = relu(bf16(C)*sc+sh) + A16 (LDS only); out = h3 @ Wo + bo.

__global__ __launch_bounds__(256) void out_fused(const uint32* __restrict__ C16,  // [N][64]
                                                 const uint32* __restrict__ A16,  // [N][64]
                                                 const float* __restrict__ colsum_multi,
                                                 const float* __restrict__ gamma,
                                                 const float* __restrict__ beta,
                                                 const float* __restrict__ Wo,
                                                 const float* __restrict__ bo,
                                                 float* __restrict__ out) {
    __shared__ float Hs[64][132];          // pad 4
    __shared__ float WoS[HID * OUT_DIM];
    __shared__ float scs[128], shb[128];
    int tid = threadIdx.x;
    for (int i = tid; i < HID * OUT_DIM; i += 256) WoS[i] = Wo[i];
    if (tid < 128) {
        float s = 0.f, q = 0.f;
        #pragma unroll
        for (int c = 0; c < 32; ++c) {
            s += colsum_multi[c * 256 + tid];
            q += colsum_multi[c * 256 + tid + 128];
        }
        float mu = s * (1.0f / N_NODES);
        float var = q * (1.0f / N_NODES) - mu * mu;
        float rstd = rsqrtf(var + BN_EPS);
        float sc = rstd * gamma[tid];
        scs[tid] = sc;
        shb[tid] = beta[tid] - mu * sc;
    }
    __syncthreads();

    int n0 = blockIdx.x * 64;
    #pragma unroll
    for (int i = 0; i < 8; ++i) {
        int lin = i * 256 + tid;           // 0..2047
        int row = lin >> 5;                // 0..63
        int colq = lin & 31;               // 4-feature group
        int n = n0 + row;
        float4 h = make_float4(0.f, 0.f, 0.f, 0.f);
        if (n < N_NODES) {
            uint2 cv = ((const uint2*)C16)[(size_t)n * 32 + colq];
            uint2 av = ((const uint2*)A16)[(size_t)n * 32 + colq];
            float c0 = bf_lo(cv.x), c1 = bf_hi(cv.x), c2 = bf_lo(cv.y), c3 = bf_hi(cv.y);
            float4 s = *(const float4*)(scs + colq * 4);
            float4 t = *(const float4*)(shb + colq * 4);
            h.x = fmaxf(c0 * s.x + t.x, 0.f) + bf_lo(av.x);
            h.y = fmaxf(c1 * s.y + t.y, 0.f) + bf_hi(av.x);
            h.z = fmaxf(c2 * s.z + t.z, 0.f) + bf_lo(av.y);
            h.w = fmaxf(c3 * s.w + t.w, 0.f) + bf_hi(av.y);
        }
        *(float4*)&Hs[row][colq * 4] = h;
    }
    __syncthreads();

    #pragma unroll
    for (int j = 0; j < 3; ++j) {
        int o = j * 256 + tid;             // 0..639
        if (o < 64 * OUT_DIM) {
            int nl = o / OUT_DIM;
            int c = o - nl * OUT_DIM;
            int n = n0 + nl;
            if (n < N_NODES) {
                float s = 0.f;
                #pragma unroll 4
                for (int k = 0; k < HID; ++k) s += Hs[nl][k] * WoS[k * OUT_DIM + c];
                out[(size_t)n * OUT_DIM + c] = s + bo[c];
            }
        }
    }
}

// ---------------- launch ----------------

extern "C" void kernel_launch(void* const* d_in, const int* in_sizes, int n_in,
                              void* d_out, int out_size, void* d_ws, size_t ws_size,
                              hipStream_t stream) {
    const float* x     = (const float*)d_in[0];
    const int*   ei    = (const int*)d_in[1];
    const int*   src   = ei;
    const int*   dst   = ei + N_EDGES;
    const float* W_in  = (const float*)d_in[2];
    const float* b_in  = (const float*)d_in[3];
    const float* Wc    = (const float*)d_in[4];
    const float* bc    = (const float*)d_in[5];
    const float* gamma = (const float*)d_in[6];
    const float* beta  = (const float*)d_in[7];
    const float* W_out = (const float*)d_in[8];
    const float* b_out = (const float*)d_in[9];
    float* out = (float*)d_out;

    char* p = (char*)d_ws;
    auto alloc = [&](size_t bytes) -> char* {
        char* q = p;
        p += (bytes + 255) & ~(size_t)255;
        return q;
    };
    unsigned short* A16 = (unsigned short*)alloc(sizeof(unsigned short) * N_NODES * HID); // residual h bf16
    unsigned short* B16 = (unsigned short*)alloc(sizeof(unsigned short) * N_NODES * HID); // messages bf16
    uint32* C16       = (uint32*)alloc(sizeof(unsigned short) * N_NODES * HID);           // aggregated bf16
    float*  dinv      = (float*)alloc(sizeof(float) * N_NODES);
    int*    deg_cnt   = (int*)alloc(sizeof(int) * (N_NODES + 1));            // last int = cursor
    int*    cursor    = deg_cnt + N_NODES;
    int*    row_start = (int*)alloc(sizeof(int) * N_NODES);
    int*    fill_ptr  = (int*)alloc(sizeof(int) * N_NODES);
    ushort_t* col_src = (ushort_t*)alloc(sizeof(ushort_t) * N_EDGES);
    unsigned short* PWin = (unsigned short*)alloc(sizeof(unsigned short) * 4096 * 8);
    unsigned short* PWc  = (unsigned short*)alloc(sizeof(unsigned short) * 3 * 2048 * 8);
    float*  colsumAll = (float*)alloc(sizeof(float) * 3 * 32 * 256);         // 32 hashed copies per layer

    // CSR build
    hipMemsetAsync(deg_cnt, 0, sizeof(int) * (N_NODES + 1), stream);
    hipMemsetAsync(colsumAll, 0, sizeof(float) * 3 * 32 * 256, stream);
    count_kernel<<<(N_EDGES + 255) / 256, 256, 0, stream>>>(dst, deg_cnt);
    assign_kernel<<<(N_NODES + 255) / 256, 256, 0, stream>>>(deg_cnt, row_start, fill_ptr, dinv, cursor);
    fill_kernel<<<(N_EDGES + 255) / 256, 256, 0, stream>>>(src, dst, fill_ptr, col_src);

    // all weight packs (W_in + 3x Wc), one dispatch
    pack_w_all<<<(4096 + 3 * 2048 + 255) / 256, 256, 0, stream>>>(W_in, Wc, PWin, PWc);

    const int gblk = (N_NODES + 63) / 64;

    // fused input projection + layer-0 message gemm: B0 = (relu(x@W_in+b) @ Wc0) * dinv
    gemm_in_fused<<<gblk, 256, 0, stream>>>(x, PWin, PWc, b_in, dinv, B16, N_NODES);

    for (int l = 0; l < 3; ++l) {
        float* colsum = colsumAll + (size_t)l * 32 * 256;
        agg_stats_kernel<<<N_NODES / 4, dim3(64, 4), 0, stream>>>(
            (const uint32*)B16, dinv, row_start, deg_cnt, col_src, bc + l * HID, C16, colsum);
        if (l == 0) {
            gemm_bn_fused<0><<<gblk, 256, 0, stream>>>(
                (const unsigned short*)C16, PWc + (size_t)1 * 2048 * 8, colsum,
                gamma, beta, dinv, A16, B16, N_NODES);
        } else if (l == 1) {
            gemm_bn_fused<1><<<gblk, 256, 0, stream>>>(
                (const unsigned short*)C16, PWc + (size_t)2 * 2048 * 8, colsum,
                gamma + HID, beta + HID, dinv, A16, B16, N_NODES);
        } else {
            out_fused<<<gblk, 256, 0, stream>>>(
                C16, (const uint32*)A16, colsum, gamma + 2 * HID, beta + 2 * HID, W_out, b_out, out);
        }
    }
}